// Round 2
// 56.112 us; speedup vs baseline: 1.2325x; 1.2325x over previous
//
#include <hip/hip_runtime.h>

// Quanvolution via Heisenberg-picture closed form.
//
// Circuit (per patch): product state |psi0> = (x)_i RX(phi_i)|0>, phi_i = p_i + w0_i
// (embedding RX and layer-0 RX fuse), then V = prod_q exp(-i*th_q/2 * X_{m_q})
// (layer-1 RX after first CNOT ring, masks m_q = columns of A^-1), measured with
// parity observables Z^{r_f}, r_f = rows of A^2 (second ring folded in).
// Masks m_q: {0,1},{1,2},{2,3},{3,4},{4,5},{5,6},{6,7},{7,8},{0,1,8}
// Rows  r_f: f0={2,4,6,8}, f1={0,2..8}, f2={1,3..8}, f3={0,2,4..8}
// (all constants inherited from the previously harness-verified kernel).
//
// Heisenberg expansion: V† Z^r V = sum over subsets S of anticommuting generators
// (popc(r&m_q) odd) of (prod cos th)(prod sin th) Z^r X_{M_S}, M_S = xor of masks.
// Product state kills any term with M_S !⊆ r (<X>=0); survivors use
// <Z> = cos(phi), <ZX> = -i sin(phi). All i-phases reduce to +-1:
//   z0: 8 terms over pair-subsets {2,3},{4,5},{6,7} (q=1,8 always cos),
//       signs -1 on (110),(011) patterns; bit b of M toggles cos<->sin(phi_b).
//   z1: cos(phi_3..8) * (C0C1 c0 c2 + S0S1 s0 s2)
//   z2: C0 * cos(phi_4..8) * (C1C2 c1 c3 + S1S2 s1 s3)
//   z3: cos(phi_5..8) * (C0C1C2C3 c0c2c4 + S0S1C2C3 s0s2c4
//                        + C0C1S2S3 c0s2s4 - S0S1S2S3 s0c2s4)
// Limits verified: th=0 -> z_f = prod_{i in r_f} cos phi_i; phi=0 -> z0 = prod C_q.
//
// One thread per output pixel (b,oy,ox); 3 channels serial; 4 filters written.
// No LDS, no shuffles, no state vector. ~36 sincos + ~150 FMA per thread.
//
// (Resubmission: previous round failed on infra — "container failed twice" —
// with no compile/correctness signal; kernel unchanged.)

static constexpr int CH = 3;
static constexpr int HOUT = 26;
static constexpr int WOUT = 26;
static constexpr int NPIX = 4 * HOUT * WOUT;  // 2704

__global__ __launch_bounds__(64) void quanv_closed(
    const float* __restrict__ x,   // (4,3,28,28) f32
    const float* __restrict__ w,   // (2,9) f32
    float* __restrict__ out)       // (4,4,26,26) f32
{
  const int pix = blockIdx.x * 64 + threadIdx.x;
  if (pix >= NPIX) return;
  const int b  = pix / (HOUT * WOUT);
  const int r  = pix % (HOUT * WOUT);
  const int oy = r / WOUT;
  const int ox = r % WOUT;

  // ---- layer-1 trig (FULL angles th_q = w[9+q]) + subset weight products ----
  float cw[9], sw[9];
#pragma unroll
  for (int q = 0; q < 9; ++q) __sincosf(w[9 + q], &sw[q], &cw[q]);

  const float CC01 = cw[0] * cw[1], SS01 = sw[0] * sw[1];
  const float CC12 = cw[1] * cw[2], SS12 = sw[1] * sw[2];
  const float CC23 = cw[2] * cw[3], SS23 = sw[2] * sw[3];
  const float CC45 = cw[4] * cw[5], SS45 = sw[4] * sw[5];
  const float CC67 = cw[6] * cw[7], SS67 = sw[6] * sw[7];
  const float C18  = cw[1] * cw[8];              // q=1,8 forced out of S for z0

  // z0 subset weights, signs folded (x1x2 ^ x2x3 parity -> -1 on 110, 011)
  const float W000 =  C18 * CC23 * CC45 * CC67;
  const float W100 =  C18 * SS23 * CC45 * CC67;
  const float W010 =  C18 * CC23 * SS45 * CC67;
  const float W001 =  C18 * CC23 * CC45 * SS67;
  const float W110 = -C18 * SS23 * SS45 * CC67;
  const float W101 =  C18 * SS23 * CC45 * SS67;
  const float W011 = -C18 * CC23 * SS45 * SS67;
  const float W111 =  C18 * SS23 * SS45 * SS67;

  const float K2a = cw[0] * CC12, K2b = cw[0] * SS12;   // z2 (q=0 forced cos)
  const float K300 =  CC01 * CC23, K310 = SS01 * CC23;  // z3 pair weights
  const float K301 =  CC01 * SS23, K311 = -SS01 * SS23;

  float acc0 = 0.f, acc1 = 0.f, acc2 = 0.f, acc3 = 0.f;

#pragma unroll
  for (int ch = 0; ch < CH; ++ch) {
    // phi_i = p_i + w0_i (full angle); patch is 3x3 at (oy,ox)
    float cf[9], sf[9];
#pragma unroll
    for (int i = 0; i < 9; ++i) {
      const int dy = i / 3, dx = i % 3;
      const float p = x[((b * CH + ch) * 28 + (oy + dy)) * 28 + (ox + dx)];
      __sincosf(p + w[i], &sf[i], &cf[i]);
    }

    // ---- z0: qubits {2,4,6,8}; bit4 toggled by x1^x2, bit6 by x2^x3 ----
    acc0 += W000 * cf[2] * cf[4] * cf[6] * cf[8]
          + W100 * sf[2] * sf[4] * cf[6] * cf[8]
          + W010 * cf[2] * sf[4] * sf[6] * cf[8]
          + W001 * cf[2] * cf[4] * sf[6] * sf[8]
          + W110 * sf[2] * cf[4] * sf[6] * cf[8]
          + W101 * sf[2] * sf[4] * sf[6] * sf[8]
          + W011 * cf[2] * sf[4] * cf[6] * sf[8]
          + W111 * sf[2] * cf[4] * cf[6] * sf[8];

    const float c5678  = cf[5] * cf[6] * cf[7] * cf[8];
    const float c45678 = cf[4] * c5678;

    // ---- z1: r1 = {0,2,3..8}, pair {0,1}, M = {0,2} ----
    acc1 += cf[3] * c45678 * (CC01 * cf[0] * cf[2] + SS01 * sf[0] * sf[2]);

    // ---- z2: r2 = {1,3,4..8}, pair {1,2}, M = {1,3} ----
    acc2 += c45678 * (K2a * cf[1] * cf[3] + K2b * sf[1] * sf[3]);

    // ---- z3: r3 = {0,2,4..8}, pairs {0,1}->{0,2}, {2,3}->{2,4} ----
    acc3 += c5678 * (K300 * cf[0] * cf[2] * cf[4]
                   + K310 * sf[0] * sf[2] * cf[4]
                   + K301 * cf[0] * sf[2] * sf[4]
                   + K311 * sf[0] * cf[2] * sf[4]);
  }

  const float inv3 = 1.f / 3.f;
  out[((b * 4 + 0) * HOUT + oy) * WOUT + ox] = acc0 * inv3;
  out[((b * 4 + 1) * HOUT + oy) * WOUT + ox] = acc1 * inv3;
  out[((b * 4 + 2) * HOUT + oy) * WOUT + ox] = acc2 * inv3;
  out[((b * 4 + 3) * HOUT + oy) * WOUT + ox] = acc3 * inv3;
}

extern "C" void kernel_launch(void* const* d_in, const int* in_sizes, int n_in,
                              void* d_out, int out_size, void* d_ws, size_t ws_size,
                              hipStream_t stream) {
  const float* x = (const float*)d_in[0];
  const float* w = (const float*)d_in[1];
  float* out = (float*)d_out;
  dim3 grid((NPIX + 63) / 64);
  dim3 block(64);
  hipLaunchKernelGGL(quanv_closed, grid, block, 0, stream, x, w, out);
}

// Round 3
// 55.364 us; speedup vs baseline: 1.2492x; 1.0135x over previous
//
#include <hip/hip_runtime.h>

// Quanvolution via Heisenberg-picture closed form — channel-parallel layout.
//
// Math identical to the round-2 verified kernel (see derivation there):
//  z0: 8 terms over pair-subsets {2,3},{4,5},{6,7} (q=1,8 forced cos),
//      signs -1 on (110),(011); z1/z2/z3 are 2/2/4-term parity sums.
// Masks m_q = cols of A^-1, rows r_f of A^2 inherited from the original
// harness-verified state-vector kernel.
//
// Layout change (latency experiment): block = 192 = 3 waves; wave = channel,
// lane = pixel-within-block (64 pixels/block). Each thread: 9 HBM-cold loads +
// 9 patch sincos + ~60 FMA (was 27/27/150 with channels serial). The three
// channel dependency chains now run on different SIMDs concurrently; a 3 KB
// LDS reduction recombines. If dur_us doesn't move, the remaining time is the
// harness's 39.9 µs workspace re-poison + dispatch overhead (= floor).

static constexpr int CH = 3;
static constexpr int HOUT = 26;
static constexpr int WOUT = 26;
static constexpr int NPIX = 4 * HOUT * WOUT;  // 2704
static constexpr int PPB = 64;                // pixels per block

__global__ __launch_bounds__(192) void quanv_closed(
    const float* __restrict__ x,   // (4,3,28,28) f32
    const float* __restrict__ w,   // (2,9) f32
    float* __restrict__ out)       // (4,4,26,26) f32
{
  __shared__ float sm[CH][PPB][4];

  const int lane = threadIdx.x & 63;
  const int ch   = threadIdx.x >> 6;          // 0..2
  int pix = blockIdx.x * PPB + lane;
  const bool valid = pix < NPIX;
  if (!valid) pix = NPIX - 1;                 // clamp: safe redundant loads
  const int b  = pix / (HOUT * WOUT);
  const int r  = pix % (HOUT * WOUT);
  const int oy = r / WOUT;
  const int ox = r % WOUT;

  // ---- issue the 9 patch loads first (independent, HBM-cold after fill) ----
  float phi[9];
#pragma unroll
  for (int i = 0; i < 9; ++i) {
    const int dy = i / 3, dx = i % 3;
    phi[i] = x[((b * CH + ch) * 28 + (oy + dy)) * 28 + (ox + dx)] + w[i];
  }

  // ---- layer-1 weights (independent of loads -> overlaps their latency) ----
  float cw[9], sw[9];
#pragma unroll
  for (int q = 0; q < 9; ++q) __sincosf(w[9 + q], &sw[q], &cw[q]);

  const float CC01 = cw[0] * cw[1], SS01 = sw[0] * sw[1];
  const float CC12 = cw[1] * cw[2], SS12 = sw[1] * sw[2];
  const float CC23 = cw[2] * cw[3], SS23 = sw[2] * sw[3];
  const float CC45 = cw[4] * cw[5], SS45 = sw[4] * sw[5];
  const float CC67 = cw[6] * cw[7], SS67 = sw[6] * sw[7];
  const float C18  = cw[1] * cw[8];

  const float W000 =  C18 * CC23 * CC45 * CC67;
  const float W100 =  C18 * SS23 * CC45 * CC67;
  const float W010 =  C18 * CC23 * SS45 * CC67;
  const float W001 =  C18 * CC23 * CC45 * SS67;
  const float W110 = -C18 * SS23 * SS45 * CC67;
  const float W101 =  C18 * SS23 * CC45 * SS67;
  const float W011 = -C18 * CC23 * SS45 * SS67;
  const float W111 =  C18 * SS23 * SS45 * SS67;

  const float K2a = cw[0] * CC12, K2b = cw[0] * SS12;
  const float K300 =  CC01 * CC23, K310 = SS01 * CC23;
  const float K301 =  CC01 * SS23, K311 = -SS01 * SS23;

  // ---- patch trig ----
  float cf[9], sf[9];
#pragma unroll
  for (int i = 0; i < 9; ++i) __sincosf(phi[i], &sf[i], &cf[i]);

  // ---- closed-form expectations (single channel) ----
  const float z0 = W000 * cf[2] * cf[4] * cf[6] * cf[8]
                 + W100 * sf[2] * sf[4] * cf[6] * cf[8]
                 + W010 * cf[2] * sf[4] * sf[6] * cf[8]
                 + W001 * cf[2] * cf[4] * sf[6] * sf[8]
                 + W110 * sf[2] * cf[4] * sf[6] * cf[8]
                 + W101 * sf[2] * sf[4] * sf[6] * sf[8]
                 + W011 * cf[2] * sf[4] * cf[6] * sf[8]
                 + W111 * sf[2] * cf[4] * cf[6] * sf[8];

  const float c5678  = cf[5] * cf[6] * cf[7] * cf[8];
  const float c45678 = cf[4] * c5678;

  const float z1 = cf[3] * c45678 * (CC01 * cf[0] * cf[2] + SS01 * sf[0] * sf[2]);
  const float z2 = c45678 * (K2a * cf[1] * cf[3] + K2b * sf[1] * sf[3]);
  const float z3 = c5678 * (K300 * cf[0] * cf[2] * cf[4]
                          + K310 * sf[0] * sf[2] * cf[4]
                          + K301 * cf[0] * sf[2] * sf[4]
                          + K311 * sf[0] * cf[2] * sf[4]);

  sm[ch][lane][0] = z0;
  sm[ch][lane][1] = z1;
  sm[ch][lane][2] = z2;
  sm[ch][lane][3] = z3;
  __syncthreads();

  // ---- channel mean + write (wave 0; its pix/b/oy/ox already correct) ----
  if (threadIdx.x < PPB && valid) {
    const float inv3 = 1.f / 3.f;
#pragma unroll
    for (int f = 0; f < 4; ++f) {
      const float v = (sm[0][lane][f] + sm[1][lane][f] + sm[2][lane][f]) * inv3;
      out[((b * 4 + f) * HOUT + oy) * WOUT + ox] = v;
    }
  }
}

extern "C" void kernel_launch(void* const* d_in, const int* in_sizes, int n_in,
                              void* d_out, int out_size, void* d_ws, size_t ws_size,
                              hipStream_t stream) {
  const float* x = (const float*)d_in[0];
  const float* w = (const float*)d_in[1];
  float* out = (float*)d_out;
  dim3 grid((NPIX + PPB - 1) / PPB);   // 43 blocks
  dim3 block(192);                     // 3 waves = 3 channels
  hipLaunchKernelGGL(quanv_closed, grid, block, 0, stream, x, w, out);
}